// Round 5
// baseline (155.868 us; speedup 1.0000x reference)
//
#include <hip/hip_runtime.h>

// Problem: TemporalAttention_54322746359850
// Identity: softmax rows sum to 1 and einsum('TNS,BNH->BNH') contracts attn over
// BOTH T and S => y == 1024*v exactly; adjacency/QK/softmax are dead code.
//   att    = (1024*(h_pred@Wv + bv)) @ Wo + bo
//   gate   = sigmoid( silu([h_pred,h_prev]@gW1 + gb1) @ gW2 + gb2 )
//   h_corr = h_prev + gate*att
//   out    = h_corr + relu([h_corr,h_prev]@mW1 + mb1) @ mW2 + mb2
// Inputs f32, output f32 (verified R2/R3/R4).
//
// R4 post-mortem: 2 waves/CU, 1024-iter dependent chain -> latency-bound, 50us.
// This version: block=512 (8 waves/CU), K split 4-ways across thread groups,
// partials combined in LDS, epilogue row-split so all waves stay busy.

#define HH 128
#define NROWS 1024
#define ROWS 4     // rows per block
#define GROUPS 4   // K-split factor; block = GROUPS*HH = 512 threads

__device__ __forceinline__ void dot_range(
    const float (*__restrict__ src)[HH],   // LDS operand rows [ROWS][HH]
    const float* __restrict__ W,           // weight base, row c matches src col c
    int cbeg, int n, int j, float acc[ROWS])
{
    #pragma unroll 8
    for (int i = 0; i < n; ++i) {
        const int c = cbeg + i;
        const float w = W[c * HH + j];
        #pragma unroll
        for (int r = 0; r < ROWS; ++r) acc[r] += src[r][c] * w;
    }
}

__global__ __launch_bounds__(GROUPS * HH) void temporal_attn_fused(
    const float* __restrict__ h_prev,
    const float* __restrict__ h_pred,
    const float* __restrict__ Wv, const float* __restrict__ bv,
    const float* __restrict__ Wo, const float* __restrict__ bo,
    const float* __restrict__ gW1, const float* __restrict__ gb1,
    const float* __restrict__ gW2, const float* __restrict__ gb2,
    const float* __restrict__ mW1, const float* __restrict__ mb1,
    const float* __restrict__ mW2, const float* __restrict__ mb2,
    float* __restrict__ out)
{
    __shared__ float sPred[ROWS][HH];
    __shared__ float sPrev[ROWS][HH];
    __shared__ float sBuf[ROWS][HH];            // a, then g1, then m1
    __shared__ float sCorr[ROWS][HH];
    __shared__ float sAtt[ROWS][HH];
    __shared__ float part[GROUPS][ROWS][HH];    // K-split partial sums

    const int tid = threadIdx.x;
    const int g   = tid >> 7;          // group 0..3 (also = epilogue row)
    const int j   = tid & (HH - 1);    // column 0..127
    const int r0  = blockIdx.x * ROWS;

    // stage inputs: thread (g,j) loads row g, col j of each activation
    sPred[g][j] = h_pred[(r0 + g) * HH + j];
    sPrev[g][j] = h_prev[(r0 + g) * HH + j];
    __syncthreads();

    float acc[ROWS];
    #define ZERO_ACC() { _Pragma("unroll") for (int r = 0; r < ROWS; ++r) acc[r] = 0.f; }
    #define STORE_PART() { _Pragma("unroll") for (int r = 0; r < ROWS; ++r) part[g][r][j] = acc[r]; }
    #define COMB() (part[0][g][j] + part[1][g][j] + part[2][g][j] + part[3][g][j])

    // ---- step 1: a = 1024*(h_pred @ Wv + bv) -> sBuf ----
    ZERO_ACC();
    dot_range(sPred, Wv, g * 32, 32, j, acc);
    STORE_PART();
    __syncthreads();
    sBuf[g][j] = 1024.f * (COMB() + bv[j]);
    __syncthreads();

    // ---- step 2: att = a @ Wo + bo -> sAtt ----
    ZERO_ACC();
    dot_range(sBuf, Wo, g * 32, 32, j, acc);
    STORE_PART();
    __syncthreads();
    sAtt[g][j] = COMB() + bo[j];
    __syncthreads();

    // ---- step 3: g1 = silu([h_pred,h_prev] @ gW1 + gb1) -> sBuf ----
    ZERO_ACC();
    if (g < 2) dot_range(sPred, gW1,            g * 64,       64, j, acc);
    else       dot_range(sPrev, gW1 + HH * HH,  (g - 2) * 64, 64, j, acc);
    STORE_PART();
    __syncthreads();
    {
        float x = COMB() + gb1[j];
        sBuf[g][j] = x / (1.f + __expf(-x));   // silu
    }
    __syncthreads();

    // ---- step 4: gate = sigmoid(g1 @ gW2 + gb2); h_corr = h_prev + gate*att -> sCorr ----
    ZERO_ACC();
    dot_range(sBuf, gW2, g * 32, 32, j, acc);
    STORE_PART();
    __syncthreads();
    {
        float gate = 1.f / (1.f + __expf(-(COMB() + gb2[j])));
        sCorr[g][j] = sPrev[g][j] + gate * sAtt[g][j];
    }
    __syncthreads();

    // ---- step 5: m1 = relu([h_corr,h_prev] @ mW1 + mb1) -> sBuf ----
    ZERO_ACC();
    if (g < 2) dot_range(sCorr, mW1,           g * 64,       64, j, acc);
    else       dot_range(sPrev, mW1 + HH * HH, (g - 2) * 64, 64, j, acc);
    STORE_PART();
    __syncthreads();
    {
        float x = COMB() + mb1[j];
        sBuf[g][j] = fmaxf(x, 0.f);
    }
    __syncthreads();

    // ---- step 6: out = h_corr + m1 @ mW2 + mb2 ----
    ZERO_ACC();
    dot_range(sBuf, mW2, g * 32, 32, j, acc);
    STORE_PART();
    __syncthreads();
    out[(r0 + g) * HH + j] = sCorr[g][j] + COMB() + mb2[j];
}

extern "C" void kernel_launch(void* const* d_in, const int* in_sizes, int n_in,
                              void* d_out, int out_size, void* d_ws, size_t ws_size,
                              hipStream_t stream) {
    // setup_inputs order:
    // 0 h_prev, 1 h_pred, 2 adj_rows, 3 adj_cols,
    // 4 Wq, 5 bq, 6 Wk, 7 bk, 8 Wv, 9 bv, 10 Wo, 11 bo,
    // 12 gW1, 13 gb1, 14 gW2, 15 gb2, 16 mW1, 17 mb1, 18 mW2, 19 mb2
    const float* h_prev = (const float*)d_in[0];
    const float* h_pred = (const float*)d_in[1];
    const float* Wv  = (const float*)d_in[8];
    const float* bv  = (const float*)d_in[9];
    const float* Wo  = (const float*)d_in[10];
    const float* bo  = (const float*)d_in[11];
    const float* gW1 = (const float*)d_in[12];
    const float* gb1 = (const float*)d_in[13];
    const float* gW2 = (const float*)d_in[14];
    const float* gb2 = (const float*)d_in[15];
    const float* mW1 = (const float*)d_in[16];
    const float* mb1 = (const float*)d_in[17];
    const float* mW2 = (const float*)d_in[18];
    const float* mb2 = (const float*)d_in[19];
    float* out = (float*)d_out;

    dim3 grid(NROWS / ROWS);     // 256 blocks -> 1 per CU
    dim3 block(GROUPS * HH);     // 512 threads = 8 waves
    hipLaunchKernelGGL(temporal_attn_fused, grid, block, 0, stream,
                       h_prev, h_pred, Wv, bv, Wo, bo,
                       gW1, gb1, gW2, gb2, mW1, mb1, mW2, mb2, out);
}

// Round 6
// 99.156 us; speedup vs baseline: 1.5719x; 1.5719x over previous
//
#include <hip/hip_runtime.h>

// Problem: TemporalAttention_54322746359850
// Identity: softmax rows sum to 1 and einsum('TNS,BNH->BNH') contracts attn over
// BOTH T and S => y == 1024*v exactly; adjacency/QK/softmax are dead code.
//   att    = (1024*(h_pred@Wv + bv)) @ Wo + bo
//   gate   = sigmoid( silu([h_pred,h_prev]@gW1 + gb1) @ gW2 + gb2 )
//   h_corr = h_prev + gate*att
//   out    = h_corr + relu([h_corr,h_prev]@mW1 + mb1) @ mW2 + mb2
// Inputs f32, output f32 (verified R2/R3/R4).
//
// R5 post-mortem: latency/issue-bound on ~2048 scalar weight-load instrs per CU.
// This version: float4 weight loads into REGISTERS (4x fewer load instrs),
// one vmcnt wait per step, dense register FMA bursts, 16-way K-split with
// conflict-free partial combine.

#define HH 128
#define NROWS 1024
#define ROWS 4      // rows per block
#define NT 512      // threads per block (8 waves)
#define NG 16       // c-groups (8 rows of W each per 128-K)

__device__ __forceinline__ void fma4(float4& a, float s, const float4& w) {
    a.x += s * w.x; a.y += s * w.y; a.z += s * w.z; a.w += s * w.w;
}

__global__ __launch_bounds__(NT) void temporal_attn_fused(
    const float* __restrict__ h_prev,
    const float* __restrict__ h_pred,
    const float* __restrict__ Wv, const float* __restrict__ bv,
    const float* __restrict__ Wo, const float* __restrict__ bo,
    const float* __restrict__ gW1, const float* __restrict__ gb1,
    const float* __restrict__ gW2, const float* __restrict__ gb2,
    const float* __restrict__ mW1, const float* __restrict__ mb1,
    const float* __restrict__ mW2, const float* __restrict__ mb2,
    float* __restrict__ out)
{
    __shared__ __align__(16) float sPred[ROWS][HH];
    __shared__ __align__(16) float sPrev[ROWS][HH];
    __shared__ __align__(16) float sBuf[ROWS][HH];   // a, then g1, then m1
    __shared__ __align__(16) float sCorr[ROWS][HH];
    __shared__ __align__(16) float sAtt[ROWS][HH];
    __shared__ float4 part4[NG][ROWS][HH / 4];       // 32 KB partials

    const int tid = threadIdx.x;
    const int jq  = tid & 31;          // j-quad: cols 4*jq .. 4*jq+3
    const int cg  = tid >> 5;          // c-group 0..15: rows 8*cg .. 8*cg+7
    const int rr  = tid >> 7;          // epilogue row 0..3
    const int jj  = tid & (HH - 1);    // epilogue col 0..127
    const int r0  = blockIdx.x * ROWS;

    // ---- stage activations (coalesced, one element per thread per array) ----
    sPred[rr][jj] = h_pred[(r0 + rr) * HH + jj];
    sPrev[rr][jj] = h_prev[(r0 + rr) * HH + jj];
    // bias prefetch for this thread's epilogue column
    const float rbv  = bv[jj],  rbo  = bo[jj];
    const float rgb1 = gb1[jj], rgb2 = gb2[jj];
    const float rmb1 = mb1[jj], rmb2 = mb2[jj];
    __syncthreads();

    const float* pf = (const float*)part4;
    const int cbase = rr * HH + jj;    // combine read base (dwords)

    float4 w[16];
    float4 acc[ROWS];

    // K=128 step: weights W[128][128], acts S[ROWS][HH]; result 'dot' per (rr,jj)
    #define LOAD_W128(W) { \
        const float4* W4 = (const float4*)(W); \
        _Pragma("unroll") for (int i = 0; i < 8; ++i) \
            w[i] = W4[(8 * cg + i) * (HH / 4) + jq]; }

    #define FMA128(S) { \
        _Pragma("unroll") for (int r = 0; r < ROWS; ++r) { \
            acc[r] = make_float4(0.f, 0.f, 0.f, 0.f); \
            float4 a0 = *(const float4*)&S[r][8 * cg]; \
            float4 a1 = *(const float4*)&S[r][8 * cg + 4]; \
            fma4(acc[r], a0.x, w[0]); fma4(acc[r], a0.y, w[1]); \
            fma4(acc[r], a0.z, w[2]); fma4(acc[r], a0.w, w[3]); \
            fma4(acc[r], a1.x, w[4]); fma4(acc[r], a1.y, w[5]); \
            fma4(acc[r], a1.z, w[6]); fma4(acc[r], a1.w, w[7]); } }

    #define LOAD_W256(W) { \
        const float4* W4 = (const float4*)(W); \
        _Pragma("unroll") for (int i = 0; i < 8; ++i) { \
            w[i]     = W4[(8 * cg + i) * (HH / 4) + jq]; \
            w[8 + i] = W4[(HH + 8 * cg + i) * (HH / 4) + jq]; } }

    #define FMA256(SA, SB) { \
        _Pragma("unroll") for (int r = 0; r < ROWS; ++r) { \
            acc[r] = make_float4(0.f, 0.f, 0.f, 0.f); \
            float4 a0 = *(const float4*)&SA[r][8 * cg]; \
            float4 a1 = *(const float4*)&SA[r][8 * cg + 4]; \
            float4 b0 = *(const float4*)&SB[r][8 * cg]; \
            float4 b1 = *(const float4*)&SB[r][8 * cg + 4]; \
            fma4(acc[r], a0.x, w[0]);  fma4(acc[r], a0.y, w[1]); \
            fma4(acc[r], a0.z, w[2]);  fma4(acc[r], a0.w, w[3]); \
            fma4(acc[r], a1.x, w[4]);  fma4(acc[r], a1.y, w[5]); \
            fma4(acc[r], a1.z, w[6]);  fma4(acc[r], a1.w, w[7]); \
            fma4(acc[r], b0.x, w[8]);  fma4(acc[r], b0.y, w[9]); \
            fma4(acc[r], b0.z, w[10]); fma4(acc[r], b0.w, w[11]); \
            fma4(acc[r], b1.x, w[12]); fma4(acc[r], b1.y, w[13]); \
            fma4(acc[r], b1.z, w[14]); fma4(acc[r], b1.w, w[15]); } }

    #define PSTORE() { \
        _Pragma("unroll") for (int r = 0; r < ROWS; ++r) part4[cg][r][jq] = acc[r]; \
        __syncthreads(); }

    #define COMBINE(dotvar) \
        float dotvar = 0.f; \
        _Pragma("unroll") for (int g = 0; g < NG; ++g) dotvar += pf[g * (ROWS * HH) + cbase];

    // ---- step 1: a = 1024*(h_pred @ Wv + bv) -> sBuf ----
    LOAD_W128(Wv);
    FMA128(sPred);
    PSTORE();
    { COMBINE(dot); sBuf[rr][jj] = 1024.f * (dot + rbv); }
    __syncthreads();

    // ---- step 2: att = a @ Wo + bo -> sAtt ----
    LOAD_W128(Wo);
    FMA128(sBuf);
    PSTORE();
    { COMBINE(dot); sAtt[rr][jj] = dot + rbo; }
    __syncthreads();

    // ---- step 3: g1 = silu([h_pred,h_prev] @ gW1 + gb1) -> sBuf ----
    LOAD_W256(gW1);
    FMA256(sPred, sPrev);
    PSTORE();
    { COMBINE(dot);
      float x = dot + rgb1;
      sBuf[rr][jj] = x / (1.f + __expf(-x)); }
    __syncthreads();

    // ---- step 4: gate = sigmoid(g1 @ gW2 + gb2); h_corr = h_prev + gate*att ----
    LOAD_W128(gW2);
    FMA128(sBuf);
    PSTORE();
    { COMBINE(dot);
      float gate = 1.f / (1.f + __expf(-(dot + rgb2)));
      sCorr[rr][jj] = sPrev[rr][jj] + gate * sAtt[rr][jj]; }
    __syncthreads();

    // ---- step 5: m1 = relu([h_corr,h_prev] @ mW1 + mb1) -> sBuf ----
    LOAD_W256(mW1);
    FMA256(sCorr, sPrev);
    PSTORE();
    { COMBINE(dot); sBuf[rr][jj] = fmaxf(dot + rmb1, 0.f); }
    __syncthreads();

    // ---- step 6: out = h_corr + m1 @ mW2 + mb2 ----
    LOAD_W128(mW2);
    FMA128(sBuf);
    PSTORE();
    { COMBINE(dot); out[(r0 + rr) * HH + jj] = sCorr[rr][jj] + dot + rmb2; }
}

extern "C" void kernel_launch(void* const* d_in, const int* in_sizes, int n_in,
                              void* d_out, int out_size, void* d_ws, size_t ws_size,
                              hipStream_t stream) {
    // setup_inputs order:
    // 0 h_prev, 1 h_pred, 2 adj_rows, 3 adj_cols,
    // 4 Wq, 5 bq, 6 Wk, 7 bk, 8 Wv, 9 bv, 10 Wo, 11 bo,
    // 12 gW1, 13 gb1, 14 gW2, 15 gb2, 16 mW1, 17 mb1, 18 mW2, 19 mb2
    const float* h_prev = (const float*)d_in[0];
    const float* h_pred = (const float*)d_in[1];
    const float* Wv  = (const float*)d_in[8];
    const float* bv  = (const float*)d_in[9];
    const float* Wo  = (const float*)d_in[10];
    const float* bo  = (const float*)d_in[11];
    const float* gW1 = (const float*)d_in[12];
    const float* gb1 = (const float*)d_in[13];
    const float* gW2 = (const float*)d_in[14];
    const float* gb2 = (const float*)d_in[15];
    const float* mW1 = (const float*)d_in[16];
    const float* mb1 = (const float*)d_in[17];
    const float* mW2 = (const float*)d_in[18];
    const float* mb2 = (const float*)d_in[19];
    float* out = (float*)d_out;

    dim3 grid(NROWS / ROWS);   // 256 blocks -> 1 per CU
    dim3 block(NT);            // 512 threads = 8 waves
    hipLaunchKernelGGL(temporal_attn_fused, grid, block, 0, stream,
                       h_prev, h_pred, Wv, bv, Wo, bo,
                       gW1, gb1, gW2, gb2, mW1, mb1, mW2, mb2, out);
}

// Round 7
// 98.731 us; speedup vs baseline: 1.5787x; 1.0043x over previous
//
#include <hip/hip_runtime.h>

// Problem: TemporalAttention_54322746359850
// Identity: softmax rows sum to 1 and einsum('TNS,BNH->BNH') contracts attn over
// BOTH T and S => y == 1024*v exactly; adjacency/QK/softmax are dead code.
//   att    = (1024*(h_pred@Wv + bv)) @ Wo + bo
//   gate   = sigmoid( silu([h_pred,h_prev]@gW1 + gb1) @ gW2 + gb2 )
//   h_corr = h_prev + gate*att
//   out    = h_corr + relu([h_corr,h_prev]@mW1 + mb1) @ mW2 + mb2
// Inputs f32, output f32 (verified R2/R3/R4).
//
// R6 post-mortem: kernel ~35us, cold caches every replay (268MB poison evicts
// L2+L3) + 256 CUs lockstep on the same weight lines. This version:
//  (a) cross-step weight prefetch (double-buffered wa/wb registers): step n+1
//      loads issue before step n's barriers, hiding miss latency;
//  (b) per-block rotation of c-group assignment so blocks first-touch
//      different weight lines (combine is order-independent).

#define HH 128
#define NROWS 1024
#define ROWS 4      // rows per block
#define NT 512      // threads per block (8 waves)
#define NG 16       // c-groups (8 K-rows of W each per 128-K)

__device__ __forceinline__ void fma4(float4& a, float s, const float4& w) {
    a.x += s * w.x; a.y += s * w.y; a.z += s * w.z; a.w += s * w.w;
}

__global__ __launch_bounds__(NT) void temporal_attn_fused(
    const float* __restrict__ h_prev,
    const float* __restrict__ h_pred,
    const float* __restrict__ Wv, const float* __restrict__ bv,
    const float* __restrict__ Wo, const float* __restrict__ bo,
    const float* __restrict__ gW1, const float* __restrict__ gb1,
    const float* __restrict__ gW2, const float* __restrict__ gb2,
    const float* __restrict__ mW1, const float* __restrict__ mb1,
    const float* __restrict__ mW2, const float* __restrict__ mb2,
    float* __restrict__ out)
{
    __shared__ __align__(16) float sPred[ROWS][HH];
    __shared__ __align__(16) float sPrev[ROWS][HH];
    __shared__ __align__(16) float sBuf[ROWS][HH];   // a, then g1, then m1
    __shared__ __align__(16) float sCorr[ROWS][HH];
    __shared__ __align__(16) float sAtt[ROWS][HH];
    __shared__ float4 part4[NG][ROWS][HH / 4];       // 32 KB partials

    const int tid = threadIdx.x;
    const int jq  = tid & 31;                        // j-quad: cols 4*jq..4*jq+3
    const int cg  = ((tid >> 5) + blockIdx.x) & 15;  // rotated c-group (hotspot spread)
    const int rr  = tid >> 7;                        // epilogue row 0..3
    const int jj  = tid & (HH - 1);                  // epilogue col 0..127
    const int r0  = blockIdx.x * ROWS;

    // ---- stage activations (coalesced) + bias prefetch ----
    sPred[rr][jj] = h_pred[(r0 + rr) * HH + jj];
    sPrev[rr][jj] = h_prev[(r0 + rr) * HH + jj];
    const float rbv  = bv[jj],  rbo  = bo[jj];
    const float rgb1 = gb1[jj], rgb2 = gb2[jj];
    const float rmb1 = mb1[jj], rmb2 = mb2[jj];
    __syncthreads();

    const float* pf = (const float*)part4;
    const int cbase = rr * HH + jj;                  // combine read base (dwords)

    float4 wa[16], wb[16];
    float4 acc[ROWS];

    #define LOAD_W128(WREG, W) { \
        const float4* W4 = (const float4*)(W); \
        _Pragma("unroll") for (int i = 0; i < 8; ++i) \
            WREG[i] = W4[(8 * cg + i) * (HH / 4) + jq]; }

    #define LOAD_W256(WREG, W) { \
        const float4* W4 = (const float4*)(W); \
        _Pragma("unroll") for (int i = 0; i < 8; ++i) { \
            WREG[i]     = W4[(8 * cg + i) * (HH / 4) + jq]; \
            WREG[8 + i] = W4[(HH + 8 * cg + i) * (HH / 4) + jq]; } }

    #define FMA128(WREG, S) { \
        _Pragma("unroll") for (int r = 0; r < ROWS; ++r) { \
            acc[r] = make_float4(0.f, 0.f, 0.f, 0.f); \
            float4 a0 = *(const float4*)&S[r][8 * cg]; \
            float4 a1 = *(const float4*)&S[r][8 * cg + 4]; \
            fma4(acc[r], a0.x, WREG[0]); fma4(acc[r], a0.y, WREG[1]); \
            fma4(acc[r], a0.z, WREG[2]); fma4(acc[r], a0.w, WREG[3]); \
            fma4(acc[r], a1.x, WREG[4]); fma4(acc[r], a1.y, WREG[5]); \
            fma4(acc[r], a1.z, WREG[6]); fma4(acc[r], a1.w, WREG[7]); } }

    #define FMA256(WREG, SA, SB) { \
        _Pragma("unroll") for (int r = 0; r < ROWS; ++r) { \
            acc[r] = make_float4(0.f, 0.f, 0.f, 0.f); \
            float4 a0 = *(const float4*)&SA[r][8 * cg]; \
            float4 a1 = *(const float4*)&SA[r][8 * cg + 4]; \
            float4 b0 = *(const float4*)&SB[r][8 * cg]; \
            float4 b1 = *(const float4*)&SB[r][8 * cg + 4]; \
            fma4(acc[r], a0.x, WREG[0]);  fma4(acc[r], a0.y, WREG[1]); \
            fma4(acc[r], a0.z, WREG[2]);  fma4(acc[r], a0.w, WREG[3]); \
            fma4(acc[r], a1.x, WREG[4]);  fma4(acc[r], a1.y, WREG[5]); \
            fma4(acc[r], a1.z, WREG[6]);  fma4(acc[r], a1.w, WREG[7]); \
            fma4(acc[r], b0.x, WREG[8]);  fma4(acc[r], b0.y, WREG[9]); \
            fma4(acc[r], b0.z, WREG[10]); fma4(acc[r], b0.w, WREG[11]); \
            fma4(acc[r], b1.x, WREG[12]); fma4(acc[r], b1.y, WREG[13]); \
            fma4(acc[r], b1.z, WREG[14]); fma4(acc[r], b1.w, WREG[15]); } }

    #define PSTORE() { \
        _Pragma("unroll") for (int r = 0; r < ROWS; ++r) part4[cg][r][jq] = acc[r]; \
        __syncthreads(); }

    #define COMBINE(dotvar) \
        float dotvar = 0.f; \
        _Pragma("unroll") for (int g = 0; g < NG; ++g) dotvar += pf[g * (ROWS * HH) + cbase];

    // ---- step 1: a = 1024*(h_pred @ Wv + bv) -> sBuf ----
    LOAD_W128(wa, Wv);      // step-1 weights
    LOAD_W128(wb, Wo);      // prefetch step-2 weights
    FMA128(wa, sPred);
    LOAD_W256(wa, gW1);     // prefetch step-3 weights (wa free after FMA above)
    PSTORE();
    { COMBINE(dot); sBuf[rr][jj] = 1024.f * (dot + rbv); }
    __syncthreads();

    // ---- step 2: att = a @ Wo + bo -> sAtt ----
    FMA128(wb, sBuf);
    LOAD_W128(wb, gW2);     // prefetch step-4 weights
    PSTORE();
    { COMBINE(dot); sAtt[rr][jj] = dot + rbo; }
    __syncthreads();

    // ---- step 3: g1 = silu([h_pred,h_prev] @ gW1 + gb1) -> sBuf ----
    FMA256(wa, sPred, sPrev);
    LOAD_W256(wa, mW1);     // prefetch step-5 weights
    PSTORE();
    { COMBINE(dot);
      float x = dot + rgb1;
      sBuf[rr][jj] = x / (1.f + __expf(-x)); }
    __syncthreads();

    // ---- step 4: gate = sigmoid(g1 @ gW2 + gb2); h_corr = h_prev + gate*att ----
    FMA128(wb, sBuf);
    LOAD_W128(wb, mW2);     // prefetch step-6 weights
    PSTORE();
    { COMBINE(dot);
      float gate = 1.f / (1.f + __expf(-(dot + rgb2)));
      sCorr[rr][jj] = sPrev[rr][jj] + gate * sAtt[rr][jj]; }
    __syncthreads();

    // ---- step 5: m1 = relu([h_corr,h_prev] @ mW1 + mb1) -> sBuf ----
    FMA256(wa, sCorr, sPrev);
    PSTORE();
    { COMBINE(dot); sBuf[rr][jj] = fmaxf(dot + rmb1, 0.f); }
    __syncthreads();

    // ---- step 6: out = h_corr + m1 @ mW2 + mb2 ----
    FMA128(wb, sBuf);
    PSTORE();
    { COMBINE(dot); out[(r0 + rr) * HH + jj] = sCorr[rr][jj] + dot + rmb2; }
}

extern "C" void kernel_launch(void* const* d_in, const int* in_sizes, int n_in,
                              void* d_out, int out_size, void* d_ws, size_t ws_size,
                              hipStream_t stream) {
    // setup_inputs order:
    // 0 h_prev, 1 h_pred, 2 adj_rows, 3 adj_cols,
    // 4 Wq, 5 bq, 6 Wk, 7 bk, 8 Wv, 9 bv, 10 Wo, 11 bo,
    // 12 gW1, 13 gb1, 14 gW2, 15 gb2, 16 mW1, 17 mb1, 18 mW2, 19 mb2
    const float* h_prev = (const float*)d_in[0];
    const float* h_pred = (const float*)d_in[1];
    const float* Wv  = (const float*)d_in[8];
    const float* bv  = (const float*)d_in[9];
    const float* Wo  = (const float*)d_in[10];
    const float* bo  = (const float*)d_in[11];
    const float* gW1 = (const float*)d_in[12];
    const float* gb1 = (const float*)d_in[13];
    const float* gW2 = (const float*)d_in[14];
    const float* gb2 = (const float*)d_in[15];
    const float* mW1 = (const float*)d_in[16];
    const float* mb1 = (const float*)d_in[17];
    const float* mW2 = (const float*)d_in[18];
    const float* mb2 = (const float*)d_in[19];
    float* out = (float*)d_out;

    dim3 grid(NROWS / ROWS);   // 256 blocks -> 1 per CU
    dim3 block(NT);            // 512 threads = 8 waves
    hipLaunchKernelGGL(temporal_attn_fused, grid, block, 0, stream,
                       h_prev, h_pred, Wv, bv, Wo, bo,
                       gW1, gb1, gW2, gb2, mW1, mb1, mW2, mb2, out);
}